// Round 5
// baseline (9276.000 us; speedup 1.0000x reference)
//
#include <hip/hip_runtime.h>
#include <math.h>

#define NB 512
#define NN 256
#define N_ITERS 400
#define KAPPA_F 0.1f

typedef _Float16 half2_t __attribute__((ext_vector_type(2)));
typedef _Float16 half8_t __attribute__((ext_vector_type(8)));

__device__ inline float fdot2f(half2_t a, half2_t b, float c) {
#if __has_builtin(__builtin_amdgcn_fdot2)
  return __builtin_amdgcn_fdot2(a, b, c, false);
#else
  return (float)a.x * (float)b.x + (float)a.y * (float)b.y + c;
#endif
}

// One block = one batch. 1024 threads = 16 waves, 4 waves/EU, 1 block/CU.
//
// R1-R3: per-thread ARRAYS get demoted to scratch (SROA runs before unroll)
//   -> NAMED vector registers only, macro-generated accesses.
// R4: kernel became critical-path-bound (~13K cyc/iter): 3 barriers/iter,
//   separate phase B, and a cold-start Michelot (4-6 rounds of 6-deep
//   ds_swizzle butterflies) in one wave while 15 waves idle.
// R5: fuse B into C (wave 0 combines partials itself), keep w/mu/tau in
//   wave-0 REGISTERS across iterations (tau warm-start -> ~2 Michelot
//   rounds), 2 barriers/iter.

#define ZERO4(J) c##J.x = 0.f; c##J.y = 0.f; c##J.z = 0.f; c##J.w = 0.f;
#define ZERO_ALL() \
  ZERO4(0) ZERO4(1) ZERO4(2) ZERO4(3) ZERO4(4) ZERO4(5) ZERO4(6) ZERO4(7) \
  ZERO4(8) ZERO4(9) ZERO4(10) ZERO4(11) ZERO4(12) ZERO4(13) ZERO4(14) ZERO4(15)

#define GACC(J) { float4 f = rowp4[J]; \
  c##J.x = fmaf(a, f.x, c##J.x); c##J.y = fmaf(a, f.y, c##J.y); \
  c##J.z = fmaf(a, f.z, c##J.z); c##J.w = fmaf(a, f.w, c##J.w); }

// Gram accumulate: c += (SRC^T SRC)[r][64q..64q+63], plus fro += ||tile||^2
#define GRAM(SRC) do { \
  const float4* __restrict__ src4 = (const float4*)(SRC); \
  ZERO_ALL(); \
  fro = 0.f; \
  float4 stage = src4[t]; \
  for (int kt = 0; kt < 16; ++kt) { \
    __syncthreads(); \
    ((float4*)As)[t] = stage; \
    fro += stage.x*stage.x + stage.y*stage.y + stage.z*stage.z + stage.w*stage.w; \
    __syncthreads(); \
    if (kt < 15) stage = src4[(kt + 1) * 1024 + t]; \
    for (int k = 0; k < 16; ++k) { \
      float a = As[k * NN + r]; \
      const float4* rowp4 = (const float4*)(As + k * NN + 64 * q); \
      GACC(0) GACC(1) GACC(2) GACC(3) GACC(4) GACC(5) GACC(6) GACC(7) \
      GACC(8) GACC(9) GACC(10) GACC(11) GACC(12) GACC(13) GACC(14) GACC(15) \
    } \
  } \
} while (0)

// Convert c(CA),c(CB) fp32 -> 4 named half2 of group G (cols 8G..8G+7)
#define CVT(G, CA, CB) { half2_t h; \
  h.x = (_Float16)c##CA.x; h.y = (_Float16)c##CA.y; g##G##0 = h; \
  h.x = (_Float16)c##CA.z; h.y = (_Float16)c##CA.w; g##G##1 = h; \
  h.x = (_Float16)c##CB.x; h.y = (_Float16)c##CB.y; g##G##2 = h; \
  h.x = (_Float16)c##CB.z; h.y = (_Float16)c##CB.w; g##G##3 = h; }

#define G1STEP(J) { float4 f = w4[J]; \
  a1 = fmaf(c##J.x, f.x, fmaf(c##J.y, f.y, fmaf(c##J.z, f.z, fmaf(c##J.w, f.w, a1)))); }

#define G2STEP(J) { half8_t u = wh8[J]; \
  a2 = fdot2f(g##J##0, __builtin_shufflevector(u, u, 0, 1), a2); \
  a2 = fdot2f(g##J##1, __builtin_shufflevector(u, u, 2, 3), a2); \
  a2 = fdot2f(g##J##2, __builtin_shufflevector(u, u, 4, 5), a2); \
  a2 = fdot2f(g##J##3, __builtin_shufflevector(u, u, 6, 7), a2); }

__global__
__attribute__((amdgpu_flat_work_group_size(1024, 1024)))
__attribute__((amdgpu_waves_per_eu(4, 4)))
void mvo_kernel(const float* __restrict__ mu,
                const float* __restrict__ U,
                const float* __restrict__ A,
                float* __restrict__ out)
{
  __shared__ alignas(16) float As[16 * NN];   // staging tile (16 rows)
  __shared__ float part1s[1024];
  __shared__ float part2s[1024];
  __shared__ alignas(16) float    wsf[NN];    // w fp32 (written by wave 0)
  __shared__ alignas(16) _Float16 whs[NN];    // w fp16 copy
  __shared__ float dslot[16];
  __shared__ float slotA[16];
  __shared__ float slotB[16];

  const int t    = threadIdx.x;
  const int b    = blockIdx.x;
  const int lane = t & 63;
  const int wv   = t >> 6;
  const int q    = t >> 8;   // column-chunk index 0..3 (wave-uniform)
  const int r    = t & 255;  // row index (lane-consecutive)

  const float* __restrict__ Ub = U + (size_t)b * NN * NN;
  const float* __restrict__ Ab = A + (size_t)b * NN * NN;

  // Named register state — G1 row-chunk (fp32) and G2 row-chunk (fp16 pairs)
  float4 c0, c1, c2, c3, c4, c5, c6, c7, c8, c9, c10, c11, c12, c13, c14, c15;
  half2_t g00, g01, g02, g03, g10, g11, g12, g13, g20, g21, g22, g23,
          g30, g31, g32, g33, g40, g41, g42, g43, g50, g51, g52, g53,
          g60, g61, g62, g63, g70, g71, g72, g73;
  float fro = 0.f;
  float d1, d2;

  // Wave-0 private PGD state (registers, loop-carried across iterations)
  float w0 = 1.0f/256.0f, w1 = 1.0f/256.0f, w2 = 1.0f/256.0f, w3 = 1.0f/256.0f;
  float mu0 = 0.f, mu1 = 0.f, mu2 = 0.f, mu3 = 0.f;
  float tau_prev = -3.0e38f;
  if (wv == 0) {
    const float* mub = mu + b * NN;
    mu0 = mub[lane]; mu1 = mub[64 + lane]; mu2 = mub[128 + lane]; mu3 = mub[192 + lane];
  }

  // ---- Gram phase: A first (-> G2, converted to fp16), then U (-> G1) ----
  GRAM(Ab);
  d2 = fro;                               // ||A||_F^2 partial (= tr(G2))
  CVT(0, 0, 1) CVT(1, 2, 3) CVT(2, 4, 5) CVT(3, 6, 7)
  CVT(4, 8, 9) CVT(5, 10, 11) CVT(6, 12, 13) CVT(7, 14, 15)
  GRAM(Ub);
  d1 = fro;                               // ||U||_F^2 partial (= tr(G1))

  // step = 1/(lambd*froU2 + kappa*froA + 1)
  #pragma unroll
  for (int m = 1; m < 64; m <<= 1) {
    d1 += __shfl_xor(d1, m, 64);
    d2 += __shfl_xor(d2, m, 64);
  }
  if (lane == 0) { slotA[wv] = d1; slotB[wv] = d2; }
  if (t < NN) { wsf[t] = 1.0f / 256.0f; whs[t] = (_Float16)(1.0f / 256.0f); }
  __syncthreads();
  float froU2 = 0.f, froA2 = 0.f;
  #pragma unroll
  for (int k = 0; k < 16; ++k) { froU2 += slotA[k]; froA2 += slotB[k]; }
  const float step = 1.0f / (froU2 + KAPPA_F * sqrtf(froA2) + 1.0f);

  // ---------------- 400 PGD iterations, 2 barriers each ----------------
  for (int it = 0; it < N_ITERS; ++it) {
    // Phase A (all 16 waves): partial matvecs from register-resident G
    float a1 = 0.f, a2 = 0.f;
    const float4* w4 = (const float4*)wsf + 16 * q;      // wave-broadcast
    G1STEP(0) G1STEP(1) G1STEP(2) G1STEP(3) G1STEP(4) G1STEP(5) G1STEP(6) G1STEP(7)
    G1STEP(8) G1STEP(9) G1STEP(10) G1STEP(11) G1STEP(12) G1STEP(13) G1STEP(14) G1STEP(15)
    const half8_t* wh8 = (const half8_t*)whs + 8 * q;    // wave-broadcast
    G2STEP(0) G2STEP(1) G2STEP(2) G2STEP(3) G2STEP(4) G2STEP(5) G2STEP(6) G2STEP(7)

    // dot(w, G2 w): per-wave butterfly, one slot per wave
    float dpart = a2 * wsf[r];
    #pragma unroll
    for (int m = 1; m < 64; m <<= 1) dpart += __shfl_xor(dpart, m, 64);
    part1s[(q << 8) + r] = a1;
    part2s[(q << 8) + r] = a2;
    if (lane == 0) dslot[wv] = dpart;
    __syncthreads();

    // Phase C (wave 0): combine partials + gradient + warm-start Michelot
    if (wv == 0) {
      const int L = lane;
      float g1_0 = part1s[L]       + part1s[256+L]       + part1s[512+L]       + part1s[768+L];
      float g1_1 = part1s[64+L]    + part1s[256+64+L]    + part1s[512+64+L]    + part1s[768+64+L];
      float g1_2 = part1s[128+L]   + part1s[256+128+L]   + part1s[512+128+L]   + part1s[768+128+L];
      float g1_3 = part1s[192+L]   + part1s[256+192+L]   + part1s[512+192+L]   + part1s[768+192+L];
      float g2_0 = part2s[L]       + part2s[256+L]       + part2s[512+L]       + part2s[768+L];
      float g2_1 = part2s[64+L]    + part2s[256+64+L]    + part2s[512+64+L]    + part2s[768+64+L];
      float g2_2 = part2s[128+L]   + part2s[256+128+L]   + part2s[512+128+L]   + part2s[768+128+L];
      float g2_3 = part2s[192+L]   + part2s[256+192+L]   + part2s[512+192+L]   + part2s[768+192+L];
      float dot = 0.f;
      #pragma unroll
      for (int k2 = 0; k2 < 16; ++k2) dot += dslot[k2];
      float nrm = sqrtf(fmaxf(dot, 1e-12f));
      float kn  = KAPPA_F / nrm;
      float v0 = w0 - step * (-mu0 + g1_0 + kn * g2_0);
      float v1 = w1 - step * (-mu1 + g1_1 + kn * g2_1);
      float v2 = w2 - step * (-mu2 + g1_2 + kn * g2_2);
      float v3 = w3 - step * (-mu3 + g1_3 + kn * g2_3);

      // Michelot with warm-started tau (unique fixed point; converges from
      // either side; c2==0 => cold restart from full support)
      float tau = tau_prev;
      float cprev = -1.f;
      for (int ms = 0; ms < 24; ++ms) {
        float s2 = (v0 > tau ? v0 : 0.f) + (v1 > tau ? v1 : 0.f)
                 + (v2 > tau ? v2 : 0.f) + (v3 > tau ? v3 : 0.f);
        float c2 = (v0 > tau ? 1.f : 0.f) + (v1 > tau ? 1.f : 0.f)
                 + (v2 > tau ? 1.f : 0.f) + (v3 > tau ? 1.f : 0.f);
        #pragma unroll
        for (int m = 1; m < 64; m <<= 1) {
          s2 += __shfl_xor(s2, m, 64);
          c2 += __shfl_xor(c2, m, 64);
        }
        if (c2 == 0.f) { tau = -3.0e38f; cprev = -1.f; continue; }
        if (c2 == cprev) break;        // support stable -> tau exact
        tau = (s2 - 1.0f) / c2;
        cprev = c2;
      }
      tau_prev = tau;
      w0 = fmaxf(v0 - tau, 0.f);
      w1 = fmaxf(v1 - tau, 0.f);
      w2 = fmaxf(v2 - tau, 0.f);
      w3 = fmaxf(v3 - tau, 0.f);
      wsf[L]       = w0; wsf[64 + L]  = w1;
      wsf[128 + L] = w2; wsf[192 + L] = w3;
      whs[L]       = (_Float16)w0; whs[64 + L]  = (_Float16)w1;
      whs[128 + L] = (_Float16)w2; whs[192 + L] = (_Float16)w3;
    }
    __syncthreads();
  }

  // Final renormalize + store straight from wave-0 registers
  if (wv == 0) {
    float s = w0 + w1 + w2 + w3;
    #pragma unroll
    for (int m = 1; m < 64; m <<= 1) s += __shfl_xor(s, m, 64);
    float inv = 1.0f / (s + 1e-12f);
    float* ob = out + b * NN;
    ob[lane]       = w0 * inv;
    ob[64 + lane]  = w1 * inv;
    ob[128 + lane] = w2 * inv;
    ob[192 + lane] = w3 * inv;
  }
}

extern "C" void kernel_launch(void* const* d_in, const int* in_sizes, int n_in,
                              void* d_out, int out_size, void* d_ws, size_t ws_size,
                              hipStream_t stream) {
  const float* mu = (const float*)d_in[0];
  const float* U  = (const float*)d_in[1];
  const float* A  = (const float*)d_in[2];
  float* out = (float*)d_out;
  hipLaunchKernelGGL(mvo_kernel, dim3(NB), dim3(1024), 0, stream, mu, U, A, out);
}